// Round 1
// 736.988 us; speedup vs baseline: 1.0619x; 1.0619x over previous
//
#include <hip/hip_runtime.h>
#include <math.h>

#define D 96
#define H 8
#define KH 12
#define S 32

typedef __attribute__((ext_vector_type(8))) short short8;
typedef __attribute__((ext_vector_type(4))) float f32x4;

#define MFMA(a, b, c) __builtin_amdgcn_mfma_f32_16x16x32_bf16(a, b, c, 0, 0, 0)

__device__ __forceinline__ float sigmoidf_(float x) { return 1.0f / (1.0f + __expf(-x)); }
__device__ __forceinline__ float siluf_(float x) { return x * sigmoidf_(x); }
__device__ __forceinline__ float slrelu_(float x) {
    // (1+a)/2 x + (1-a)/2 x (2s-1) with a=0.2  ==  x*(0.2 + 0.8*s)
    return x * (0.2f + 0.8f * sigmoidf_(x));
}
__device__ __forceinline__ short f2bf(float f) {
    unsigned int u = __float_as_uint(f);
    u += 0x7fffu + ((u >> 16) & 1u);
    return (short)(u >> 16);
}
__device__ __forceinline__ float bf2f(ushort u) {
    return __uint_as_float(((unsigned int)u) << 16);
}

// Compile-time + lgkm fence for cross-type (short<->float) LDS slab reuse.
#define LDSFENCE() do { \
    asm volatile("s_waitcnt lgkmcnt(0)" ::: "memory"); \
    __builtin_amdgcn_sched_barrier(0); \
} while (0)

// ---------------------------------------------------------------------------
// Pack weights into MFMA B-fragment-ready bf16 layout. 80 frags total:
//   0..1  W1(32x32)  2..7  W2(32x96)  8..25 Walpha  26..43 Wlin
//   44..61 Wlin2     62..79 Wproj     (all 96x96 use t=/3, f=%3)
// Lane l of frag holds B[k = f*32 + (l>>4)*8 + j][n = t*16 + (l&15)], j=0..7.
// ---------------------------------------------------------------------------
__global__ void pack_weights_kernel(
    const float* __restrict__ W1, const float* __restrict__ W2,
    const float* __restrict__ WA, const float* __restrict__ WL,
    const float* __restrict__ WL2, const float* __restrict__ WP,
    short* __restrict__ wB)
{
    int tid = blockIdx.x * 256 + threadIdx.x;
    if (tid >= 80 * 512) return;
    int j    = tid & 7;
    int lane = (tid >> 3) & 63;
    int fi   = tid >> 9;
    int q = lane >> 4, ln = lane & 15;
    const float* src; int ncols, tt, ff;
    if (fi < 2)       { src = W1;  ncols = 32; tt = fi;            ff = 0; }
    else if (fi < 8)  { src = W2;  ncols = 96; tt = fi - 2;        ff = 0; }
    else if (fi < 26) { src = WA;  ncols = 96; tt = (fi - 8) / 3;  ff = (fi - 8) % 3; }
    else if (fi < 44) { src = WL;  ncols = 96; tt = (fi - 26) / 3; ff = (fi - 26) % 3; }
    else if (fi < 62) { src = WL2; ncols = 96; tt = (fi - 44) / 3; ff = (fi - 44) % 3; }
    else              { src = WP;  ncols = 96; tt = (fi - 62) / 3; ff = (fi - 62) % 3; }
    int k = ff * 32 + q * 8 + j;
    int n = tt * 16 + ln;
    wB[tid] = f2bf(src[k * ncols + n]);
}

// ---------------------------------------------------------------------------
// row_ptr[n] = first edge with dst >= n (edge_dst sorted). rp has N+1 entries.
// ---------------------------------------------------------------------------
__global__ __launch_bounds__(256) void rowptr_kernel(
    const int* __restrict__ dst, int* __restrict__ rp, int E, int N)
{
    int e = blockIdx.x * 256 + threadIdx.x;
    if (e >= E) return;
    int cur  = dst[e];
    int prev = (e == 0) ? -1 : dst[e - 1];
    for (int n = prev + 1; n <= cur; n++) rp[n] = e;
    if (e == E - 1)
        for (int n = cur + 1; n <= N; n++) rp[n] = E;
}

// ---------------------------------------------------------------------------
// Fused edge pipeline, BARRIER-FREE: every LDS producer/consumer pair is
// wave-local (wave w owns rows w*16..w*16+15 of everything). Each wave gets a
// private 3328 B slab serving two views:
//   short view: 16 rows x stride 104 shorts (bf16 staging, A<->C relayout)
//   float view: 16 rows x stride 50 floats  (slrelu scratch, 48 cols/half)
// LDS/block = 4*3328 = 13312 B -> 8 blocks/CU (32 waves, was 6 blocks/24).
// ---------------------------------------------------------------------------
__global__ __launch_bounds__(256, 8) void fused_edge_kernel(
    const float* __restrict__ message, const float* __restrict__ ea,
    const float* __restrict__ xs,
    const float* __restrict__ b1, const float* __restrict__ b2,
    const float* __restrict__ wdtp2, const float* __restrict__ adot,
    const short* __restrict__ wB,
    ushort* __restrict__ value, float* __restrict__ logits, int E)
{
    __shared__ __align__(16) char uni[4][3328];
    const short8* wB8 = (const short8*)wB;

    const int t    = threadIdx.x;
    const int lane = t & 63;
    const int w    = t >> 6;
    const int q    = lane >> 4;
    const int ln   = lane & 15;
    const int row0 = blockIdx.x * 64 + w * 16;   // wave's first edge

    short* sB = (short*)(uni[w]);
    float* sS = (float*)(uni[w]);

    const int Ec = E - 1;
    const int gA = min(row0 + ln, Ec);   // A-side row (clamped; OOB rows never stored)
    const int rA = ln;                   // local A row
    const int rC = q * 4;                // local C row base

    float eaR[4];
    int   gCc[4];
    bool  okC[4];
#pragma unroll
    for (int r = 0; r < 4; r++) {
        int g  = row0 + rC + r;
        okC[r] = (g < E);
        gCc[r] = min(g, Ec);
        eaR[r] = ea[gCc[r]];
    }

    // ---- A1: hid = silu(xs @ W1 + b1) -> sB cols 0..31 ----
    {
        const float4* p = (const float4*)&xs[(size_t)gA * S + q * 8];
        float4 x0 = p[0], x1 = p[1];
        short8 af;
        af[0] = f2bf(x0.x); af[1] = f2bf(x0.y); af[2] = f2bf(x0.z); af[3] = f2bf(x0.w);
        af[4] = f2bf(x1.x); af[5] = f2bf(x1.y); af[6] = f2bf(x1.z); af[7] = f2bf(x1.w);
        f32x4 h0 = {0, 0, 0, 0}, h1 = {0, 0, 0, 0};
        h0 = MFMA(af, wB8[0 * 64 + lane], h0);
        h1 = MFMA(af, wB8[1 * 64 + lane], h1);
        float bb0 = b1[ln], bb1 = b1[16 + ln];
#pragma unroll
        for (int r = 0; r < 4; r++) {
            sB[(rC + r) * 104 + ln]      = f2bf(siluf_(h0[r] + bb0));
            sB[(rC + r) * 104 + 16 + ln] = f2bf(siluf_(h1[r] + bb1));
        }
    }

    // ---- A2: weight = hid@W2 + b2; msg = message*ea*weight -> sB ----
    f32x4 acc[6];
    {
        short8 hf = *(const short8*)&sB[rA * 104 + q * 8];
#pragma unroll
        for (int i = 0; i < 6; i++) acc[i] = (f32x4){0, 0, 0, 0};
#pragma unroll
        for (int i = 0; i < 6; i++) acc[i] = MFMA(hf, wB8[(2 + i) * 64 + lane], acc[i]);
    }
#pragma unroll
    for (int i = 0; i < 6; i++) {
        int n = i * 16 + ln;
        float bb = b2[n];
#pragma unroll
        for (int r = 0; r < 4; r++) {
            float mv = message[(size_t)gCc[r] * D + n];
            sB[(rC + r) * 104 + n] = f2bf(mv * eaR[r] * (acc[i][r] + bb));
        }
    }

    short8 mf0 = *(const short8*)&sB[rA * 104 + 0  + q * 8];
    short8 mf1 = *(const short8*)&sB[rA * 104 + 32 + q * 8];
    short8 mf2 = *(const short8*)&sB[rA * 104 + 64 + q * 8];
    LDSFENCE();   // msg frags in regs before f32 slrelu overwrites (cross-type)

    // ---- B: P1 = msg @ W_alpha; slrelu + logits in two 48-col halves ----
#pragma unroll
    for (int i = 0; i < 6; i++) acc[i] = (f32x4){0, 0, 0, 0};
#pragma unroll
    for (int i = 0; i < 6; i++) {
        acc[i] = MFMA(mf0, wB8[(8 + i * 3 + 0) * 64 + lane], acc[i]);
        acc[i] = MFMA(mf1, wB8[(8 + i * 3 + 1) * 64 + lane], acc[i]);
        acc[i] = MFMA(mf2, wB8[(8 + i * 3 + 2) * 64 + lane], acc[i]);
    }
    {
        const int rloc = lane >> 2, hh = lane & 3;
        const int gm = row0 + rloc;
        const bool ok = (gm < E);
#pragma unroll
        for (int half = 0; half < 2; half++) {
#pragma unroll
            for (int i = 0; i < 3; i++) {
                int ii = half * 3 + i;
#pragma unroll
                for (int r = 0; r < 4; r++)
                    sS[(rC + r) * 50 + i * 16 + ln] = slrelu_(acc[ii][r]);
            }
            // wave-local reduce: lane -> (row = lane>>2, head = half*4 + (lane&3))
            int h = half * 4 + hh;
            float lg = 0.0f;
#pragma unroll
            for (int k = 0; k < KH; k++)
                lg += sS[rloc * 50 + hh * KH + k] * adot[h * KH + k];
            if (ok) logits[(size_t)gm * H + h] = lg;
        }
    }
    LDSFENCE();   // f32 reduce reads done before C1 bf16 writes (cross-type)

    // ---- C1: A2val = silu(msg@W_lin)*ea*wdtp2 -> sB ----
#pragma unroll
    for (int i = 0; i < 6; i++) acc[i] = (f32x4){0, 0, 0, 0};
#pragma unroll
    for (int i = 0; i < 6; i++) {
        acc[i] = MFMA(mf0, wB8[(26 + i * 3 + 0) * 64 + lane], acc[i]);
        acc[i] = MFMA(mf1, wB8[(26 + i * 3 + 1) * 64 + lane], acc[i]);
        acc[i] = MFMA(mf2, wB8[(26 + i * 3 + 2) * 64 + lane], acc[i]);
    }
#pragma unroll
    for (int i = 0; i < 6; i++) {
        int n = i * 16 + ln;
        float wd = wdtp2[n];
#pragma unroll
        for (int r = 0; r < 4; r++)
            sB[(rC + r) * 104 + n] = f2bf(siluf_(acc[i][r]) * eaR[r] * wd);
    }

    // ---- C2: value = A2val @ W_lin2; stage in LDS, 16B coalesced stores ----
    {
        short8 vf0 = *(const short8*)&sB[rA * 104 + 0  + q * 8];
        short8 vf1 = *(const short8*)&sB[rA * 104 + 32 + q * 8];
        short8 vf2 = *(const short8*)&sB[rA * 104 + 64 + q * 8];
#pragma unroll
        for (int i = 0; i < 6; i++) acc[i] = (f32x4){0, 0, 0, 0};
#pragma unroll
        for (int i = 0; i < 6; i++) {
            acc[i] = MFMA(vf0, wB8[(44 + i * 3 + 0) * 64 + lane], acc[i]);
            acc[i] = MFMA(vf1, wB8[(44 + i * 3 + 1) * 64 + lane], acc[i]);
            acc[i] = MFMA(vf2, wB8[(44 + i * 3 + 2) * 64 + lane], acc[i]);
        }
#pragma unroll
        for (int i = 0; i < 6; i++) {
            int n = i * 16 + ln;
#pragma unroll
            for (int r = 0; r < 4; r++)
                sB[(rC + r) * 104 + n] = f2bf(acc[i][r]);
        }
        // lane -> row lane>>2, 16B chunks (lane&3)+{0,4,8}
        const int rloc = lane >> 2, c0 = lane & 3;
        const int gm = row0 + rloc;
        if (gm < E) {
#pragma unroll
            for (int j = 0; j < 3; j++) {
                short8 v = *(const short8*)&sB[rloc * 104 + (c0 + 4 * j) * 8];
                *(short8*)&value[(size_t)gm * D + (c0 + 4 * j) * 8] = v;
            }
        }
    }
}

// ---------------------------------------------------------------------------
// Fused segment softmax + weighted aggregation: ONE WAVE PER NODE.
// Phase 1: lanes = (8 edges x 8 heads), coalesced 256B logits reads,
//          shfl_xor(8/16/32) reductions -> every lane holds m,z of h=lane&7.
// Phase 2: lanes 0..47 each own a 2-column pair (one uint of bf16 value),
//          stream value rows exactly once (192B/row, coalesced), recompute
//          alpha = exp(logit - m) on the fly, normalize by 1/z at the end.
// Replaces logz_alpha + aggregate (kills alphaU/zinv traffic ~100 MB).
// ---------------------------------------------------------------------------
__global__ __launch_bounds__(256) void node_kernel(
    const float* __restrict__ logits, const ushort* __restrict__ value,
    const int* __restrict__ rp, ushort* __restrict__ attnB, int N)
{
    const int wid  = (blockIdx.x * 256 + threadIdx.x) >> 6;  // node id
    const int lane = threadIdx.x & 63;
    if (wid >= N) return;
    const int s  = rp[wid];
    const int e1 = rp[wid + 1];

    const int h = lane & 7, eo = lane >> 3;
    float m = -INFINITY;
    for (int e = s + eo; e < e1; e += 8)
        m = fmaxf(m, logits[(size_t)e * H + h]);
    m = fmaxf(m, __shfl_xor(m, 8));
    m = fmaxf(m, __shfl_xor(m, 16));
    m = fmaxf(m, __shfl_xor(m, 32));
    float z = 0.0f;
    for (int e = s + eo; e < e1; e += 8)
        z += __expf(logits[(size_t)e * H + h] - m);
    z += __shfl_xor(z, 8);
    z += __shfl_xor(z, 16);
    z += __shfl_xor(z, 32);
    // every lane now holds m,z for head (lane&7)

    if (lane < 48) {
        const int   hc  = lane / 6;           // head of this column pair
        const float mh  = __shfl(m, hc);      // lane hc holds head hc
        const float zv  = __shfl(z, hc);
        const float zih = (zv > 0.0f) ? (1.0f / zv) : 0.0f;
        const int c = 2 * lane;
        float a0 = 0.0f, a1 = 0.0f;
        for (int e = s; e < e1; e++) {
            float a = __expf(logits[(size_t)e * H + hc] - mh);
            unsigned v = *(const unsigned*)&value[(size_t)e * D + c];
            a0 += __uint_as_float(v << 16) * a;
            a1 += __uint_as_float(v & 0xffff0000u) * a;
        }
        unsigned lo = (unsigned)(ushort)f2bf(a0 * zih);
        unsigned hi = (unsigned)(ushort)f2bf(a1 * zih);
        *(unsigned*)&attnB[(size_t)wid * D + c] = lo | (hi << 16);
    }
}

// ---------------------------------------------------------------------------
// proj: out = attn(bf16) @ W_proj via MFMA. W_proj frags 62..79 in wB.
// ---------------------------------------------------------------------------
__global__ __launch_bounds__(256) void proj_kernel(
    const ushort* __restrict__ attnB, const short* __restrict__ wB,
    float* __restrict__ out, int rows)
{
    const short8* wB8 = (const short8*)wB;
    const int t    = threadIdx.x;
    const int lane = t & 63;
    const int w    = t >> 6;
    const int q    = lane >> 4;
    const int ln   = lane & 15;
    const int row0 = blockIdx.x * 64;
    const int mA   = w * 16 + ln;
    const int gA   = row0 + mA;
    const int mC   = w * 16 + q * 4;

    short8 mf0 = {0, 0, 0, 0, 0, 0, 0, 0}, mf1 = mf0, mf2 = mf0;
    if (gA < rows) {
        mf0 = *(const short8*)&attnB[(size_t)gA * D + 0  + q * 8];
        mf1 = *(const short8*)&attnB[(size_t)gA * D + 32 + q * 8];
        mf2 = *(const short8*)&attnB[(size_t)gA * D + 64 + q * 8];
    }
    f32x4 acc[6];
#pragma unroll
    for (int i = 0; i < 6; i++) acc[i] = (f32x4){0, 0, 0, 0};
#pragma unroll
    for (int i = 0; i < 6; i++) {
        acc[i] = MFMA(mf0, wB8[(62 + i * 3 + 0) * 64 + lane], acc[i]);
        acc[i] = MFMA(mf1, wB8[(62 + i * 3 + 1) * 64 + lane], acc[i]);
        acc[i] = MFMA(mf2, wB8[(62 + i * 3 + 2) * 64 + lane], acc[i]);
    }
#pragma unroll
    for (int i = 0; i < 6; i++) {
        int nn = i * 16 + ln;
#pragma unroll
        for (int r = 0; r < 4; r++) {
            int gm = row0 + mC + r;
            if (gm < rows) out[(size_t)gm * D + nn] = acc[i][r];
        }
    }
}

// ---------------------------------------------------------------------------
extern "C" void kernel_launch(void* const* d_in, const int* in_sizes, int n_in,
                              void* d_out, int out_size, void* d_ws, size_t ws_size,
                              hipStream_t stream)
{
    const float* message      = (const float*)d_in[0];
    const float* edge_attr    = (const float*)d_in[1];
    const float* edge_scalars = (const float*)d_in[2];
    const float* W_rad1       = (const float*)d_in[3];
    const float* b_rad1       = (const float*)d_in[4];
    const float* W_rad2       = (const float*)d_in[5];
    const float* b_rad2       = (const float*)d_in[6];
    const float* W_alpha      = (const float*)d_in[7];
    const float* W_lin        = (const float*)d_in[8];
    const float* w_dtp2       = (const float*)d_in[9];
    const float* W_lin2       = (const float*)d_in[10];
    const float* alpha_dot    = (const float*)d_in[11];
    const float* W_proj       = (const float*)d_in[12];
    const int*   edge_dst     = (const int*)d_in[13];
    float* out = (float*)d_out;

    const int E = in_sizes[0] / D;
    const int N = out_size / D;

    char* p = (char*)d_ws;
    ushort* value  = (ushort*)p;  p += (size_t)E * D * 2;
    float*  logits = (float*)p;   p += (size_t)E * H * 4;
    ushort* attnB  = (ushort*)p;  p += ((size_t)N * D * 2 + 15) & ~(size_t)15;
    int*    rp     = (int*)p;     p += ((size_t)(N + 1) * 4 + 15) & ~(size_t)15;
    short*  wBuf   = (short*)p;   // 80*512 bf16

    pack_weights_kernel<<<(80 * 512 + 255) / 256, 256, 0, stream>>>(
        W_rad1, W_rad2, W_alpha, W_lin, W_lin2, W_proj, wBuf);
    rowptr_kernel<<<(E + 255) / 256, 256, 0, stream>>>(edge_dst, rp, E, N);
    fused_edge_kernel<<<(E + 63) / 64, 256, 0, stream>>>(
        message, edge_attr, edge_scalars, b_rad1, b_rad2, w_dtp2, alpha_dot,
        wBuf, value, logits, E);
    node_kernel<<<(N + 3) / 4, 256, 0, stream>>>(logits, value, rp, attnB, N);
    proj_kernel<<<(N + 63) / 64, 256, 0, stream>>>(attnB, wBuf, out, N);
}

// Round 2
// 717.679 us; speedup vs baseline: 1.0905x; 1.0269x over previous
//
#include <hip/hip_runtime.h>
#include <hip/hip_bf16.h>
#include <math.h>

#define D 96
#define H 8
#define KH 12
#define S 32

typedef __attribute__((ext_vector_type(8))) short short8;
typedef __attribute__((ext_vector_type(4))) float f32x4;

#define MFMA(a, b, c) __builtin_amdgcn_mfma_f32_16x16x32_bf16(a, b, c, 0, 0, 0)

__device__ __forceinline__ float sigmoidf_(float x) { return 1.0f / (1.0f + __expf(-x)); }
__device__ __forceinline__ float siluf_(float x) { return x * sigmoidf_(x); }
__device__ __forceinline__ float slrelu_(float x) {
    // (1+a)/2 x + (1-a)/2 x (2s-1) with a=0.2  ==  x*(0.2 + 0.8*s)
    return x * (0.2f + 0.8f * sigmoidf_(x));
}
// Plain cast -> compiler emits native gfx950 bf16 converts (and packs pairs).
__device__ __forceinline__ short f2bf(float f) {
    union { __hip_bfloat16 h; short s; } u;
    u.h = __float2bfloat16(f);
    return u.s;
}
__device__ __forceinline__ float bf2f(ushort u) {
    return __uint_as_float(((unsigned int)u) << 16);
}

// ---------------------------------------------------------------------------
// Pack weights into MFMA B-fragment-ready bf16 layout. 83 frags total:
//   0..1  W1(32x32)  2..7  W2(32x96)  8..25 Walpha  26..43 Wlin
//   44..61 Wlin2     62..79 Wproj     80..82 block-diag Adot (96x16)
// Lane l of frag holds B[k = f*32 + (l>>4)*8 + j][n = t*16 + (l&15)], j=0..7.
// Adot block-diag: B[c][h] = adot[h][c-12h] for 12h <= c < 12h+12, h<8; else 0.
// ---------------------------------------------------------------------------
__global__ void pack_weights_kernel(
    const float* __restrict__ W1, const float* __restrict__ W2,
    const float* __restrict__ WA, const float* __restrict__ WL,
    const float* __restrict__ WL2, const float* __restrict__ WP,
    const float* __restrict__ AD,
    short* __restrict__ wB)
{
    int tid = blockIdx.x * 256 + threadIdx.x;
    if (tid >= 83 * 512) return;
    int j    = tid & 7;
    int lane = (tid >> 3) & 63;
    int fi   = tid >> 9;
    int q = lane >> 4, ln = lane & 15;
    if (fi >= 80) {
        int k = (fi - 80) * 32 + q * 8 + j;   // channel 0..95
        int n = ln;                           // col (head) 0..15
        float v = 0.0f;
        if (n < 8) {
            int base = n * KH;
            if (k >= base && k < base + KH) v = AD[n * KH + (k - base)];
        }
        wB[tid] = f2bf(v);
        return;
    }
    const float* src; int ncols, tt, ff;
    if (fi < 2)       { src = W1;  ncols = 32; tt = fi;            ff = 0; }
    else if (fi < 8)  { src = W2;  ncols = 96; tt = fi - 2;        ff = 0; }
    else if (fi < 26) { src = WA;  ncols = 96; tt = (fi - 8) / 3;  ff = (fi - 8) % 3; }
    else if (fi < 44) { src = WL;  ncols = 96; tt = (fi - 26) / 3; ff = (fi - 26) % 3; }
    else if (fi < 62) { src = WL2; ncols = 96; tt = (fi - 44) / 3; ff = (fi - 44) % 3; }
    else              { src = WP;  ncols = 96; tt = (fi - 62) / 3; ff = (fi - 62) % 3; }
    int k = ff * 32 + q * 8 + j;
    int n = tt * 16 + ln;
    wB[tid] = f2bf(src[k * ncols + n]);
}

// ---------------------------------------------------------------------------
// row_ptr[n] = first edge with dst >= n (edge_dst sorted). rp has N+1 entries.
// ---------------------------------------------------------------------------
__global__ __launch_bounds__(256) void rowptr_kernel(
    const int* __restrict__ dst, int* __restrict__ rp, int E, int N)
{
    int e = blockIdx.x * 256 + threadIdx.x;
    if (e >= E) return;
    int cur  = dst[e];
    int prev = (e == 0) ? -1 : dst[e - 1];
    for (int n = prev + 1; n <= cur; n++) rp[n] = e;
    if (e == E - 1)
        for (int n = cur + 1; n <= N; n++) rp[n] = E;
}

// ---------------------------------------------------------------------------
// Fused edge pipeline, BARRIER-FREE: every LDS producer/consumer pair is
// wave-local (wave w owns rows w*16..w*16+15 of all staging). Per-wave slab:
// 16 rows x 104 shorts (bf16 only; no f32 view -> no cross-type fences).
// LDS/block = 4*3328 = 13312 B -> 8 blocks/CU (32 waves).
// Staging sequence in slab: hid -> weight -> la -> A2val -> value.
// message multiply is done in A-space with float4 loads (no C-space scalars).
// logits computed by 3 MFMAs vs block-diag Adot (frags 80..82).
// ---------------------------------------------------------------------------
__global__ __launch_bounds__(256, 8) void fused_edge_kernel(
    const float* __restrict__ message, const float* __restrict__ ea,
    const float* __restrict__ xs,
    const float* __restrict__ b1, const float* __restrict__ b2,
    const float* __restrict__ wdtp2,
    const short* __restrict__ wB,
    ushort* __restrict__ value, float* __restrict__ logits, int E)
{
    __shared__ __align__(16) short uni[4][16 * 104];
    const short8* wB8 = (const short8*)wB;

    const int t    = threadIdx.x;
    const int lane = t & 63;
    const int w    = t >> 6;
    const int q    = lane >> 4;
    const int ln   = lane & 15;
    const int row0 = blockIdx.x * 64 + w * 16;   // wave's first edge

    short* sB = uni[w];

    const int Ec = E - 1;
    const int gA = min(row0 + ln, Ec);   // A-side row (clamped; OOB never stored)
    const int rA = ln;                   // local A row
    const int rC = q * 4;                // local C row base

    float eaR[4];
    int   gCc[4];
#pragma unroll
    for (int r = 0; r < 4; r++) {
        int g  = row0 + rC + r;
        gCc[r] = min(g, Ec);
        eaR[r] = ea[gCc[r]];
    }

    // ---- A1: hid = silu(xs @ W1 + b1) -> sB cols 0..31 ----
    {
        const float4* p = (const float4*)&xs[(size_t)gA * S + q * 8];
        float4 x0 = p[0], x1 = p[1];
        short8 af;
        af[0] = f2bf(x0.x); af[1] = f2bf(x0.y); af[2] = f2bf(x0.z); af[3] = f2bf(x0.w);
        af[4] = f2bf(x1.x); af[5] = f2bf(x1.y); af[6] = f2bf(x1.z); af[7] = f2bf(x1.w);
        f32x4 h0 = {0, 0, 0, 0}, h1 = {0, 0, 0, 0};
        h0 = MFMA(af, wB8[0 * 64 + lane], h0);
        h1 = MFMA(af, wB8[1 * 64 + lane], h1);
        float bb0 = b1[ln], bb1 = b1[16 + ln];
#pragma unroll
        for (int r = 0; r < 4; r++) {
            sB[(rC + r) * 104 + ln]      = f2bf(siluf_(h0[r] + bb0));
            sB[(rC + r) * 104 + 16 + ln] = f2bf(siluf_(h1[r] + bb1));
        }
    }

    // ---- A2a: weight = hid@W2 + b2 -> sB (bf16) ----
    f32x4 acc[6];
    {
        short8 hf = *(const short8*)&sB[rA * 104 + q * 8];
#pragma unroll
        for (int i = 0; i < 6; i++) acc[i] = (f32x4){0, 0, 0, 0};
#pragma unroll
        for (int i = 0; i < 6; i++) acc[i] = MFMA(hf, wB8[(2 + i) * 64 + lane], acc[i]);
    }
#pragma unroll
    for (int i = 0; i < 6; i++) {
        int n = i * 16 + ln;
        float bb = b2[n];
#pragma unroll
        for (int r = 0; r < 4; r++)
            sB[(rC + r) * 104 + n] = f2bf(acc[i][r] + bb);
    }

    // ---- A2b: msg frags = weight * message * ea, all in A-space ----
    short8 mfa[3];
    {
        const float eaA = ea[gA];
#pragma unroll
        for (int f = 0; f < 3; f++) {
            const float4* mp = (const float4*)&message[(size_t)gA * D + f * 32 + q * 8];
            float4 m0 = mp[0], m1 = mp[1];
            short8 wf = *(const short8*)&sB[rA * 104 + f * 32 + q * 8];
            short8 r;
            r[0] = f2bf(bf2f((ushort)wf[0]) * (m0.x * eaA));
            r[1] = f2bf(bf2f((ushort)wf[1]) * (m0.y * eaA));
            r[2] = f2bf(bf2f((ushort)wf[2]) * (m0.z * eaA));
            r[3] = f2bf(bf2f((ushort)wf[3]) * (m0.w * eaA));
            r[4] = f2bf(bf2f((ushort)wf[4]) * (m1.x * eaA));
            r[5] = f2bf(bf2f((ushort)wf[5]) * (m1.y * eaA));
            r[6] = f2bf(bf2f((ushort)wf[6]) * (m1.z * eaA));
            r[7] = f2bf(bf2f((ushort)wf[7]) * (m1.w * eaA));
            mfa[f] = r;
        }
    }
    const short8 mf0 = mfa[0], mf1 = mfa[1], mf2 = mfa[2];

    // ---- B: la = slrelu(msg @ W_alpha) -> sB bf16; logits via 3 MFMA ----
#pragma unroll
    for (int i = 0; i < 6; i++) acc[i] = (f32x4){0, 0, 0, 0};
#pragma unroll
    for (int i = 0; i < 6; i++) {
        acc[i] = MFMA(mf0, wB8[(8 + i * 3 + 0) * 64 + lane], acc[i]);
        acc[i] = MFMA(mf1, wB8[(8 + i * 3 + 1) * 64 + lane], acc[i]);
        acc[i] = MFMA(mf2, wB8[(8 + i * 3 + 2) * 64 + lane], acc[i]);
    }
#pragma unroll
    for (int i = 0; i < 6; i++) {
        int n = i * 16 + ln;
#pragma unroll
        for (int r = 0; r < 4; r++)
            sB[(rC + r) * 104 + n] = f2bf(slrelu_(acc[i][r]));
    }
    {
        short8 la0 = *(const short8*)&sB[rA * 104 + 0  + q * 8];
        short8 la1 = *(const short8*)&sB[rA * 104 + 32 + q * 8];
        short8 la2 = *(const short8*)&sB[rA * 104 + 64 + q * 8];
        f32x4 lacc = {0, 0, 0, 0};
        lacc = MFMA(la0, wB8[80 * 64 + lane], lacc);
        lacc = MFMA(la1, wB8[81 * 64 + lane], lacc);
        lacc = MFMA(la2, wB8[82 * 64 + lane], lacc);
        if (ln < 8) {
#pragma unroll
            for (int r = 0; r < 4; r++) {
                int gm = row0 + rC + r;
                if (gm < E) logits[(size_t)gm * H + ln] = lacc[r];
            }
        }
    }

    // ---- C1: A2val = silu(msg@W_lin)*ea*wdtp2 -> sB ----
#pragma unroll
    for (int i = 0; i < 6; i++) acc[i] = (f32x4){0, 0, 0, 0};
#pragma unroll
    for (int i = 0; i < 6; i++) {
        acc[i] = MFMA(mf0, wB8[(26 + i * 3 + 0) * 64 + lane], acc[i]);
        acc[i] = MFMA(mf1, wB8[(26 + i * 3 + 1) * 64 + lane], acc[i]);
        acc[i] = MFMA(mf2, wB8[(26 + i * 3 + 2) * 64 + lane], acc[i]);
    }
#pragma unroll
    for (int i = 0; i < 6; i++) {
        int n = i * 16 + ln;
        float wd = wdtp2[n];
#pragma unroll
        for (int r = 0; r < 4; r++)
            sB[(rC + r) * 104 + n] = f2bf(siluf_(acc[i][r]) * eaR[r] * wd);
    }

    // ---- C2: value = A2val @ W_lin2; stage in LDS, 16B coalesced stores ----
    {
        short8 vf0 = *(const short8*)&sB[rA * 104 + 0  + q * 8];
        short8 vf1 = *(const short8*)&sB[rA * 104 + 32 + q * 8];
        short8 vf2 = *(const short8*)&sB[rA * 104 + 64 + q * 8];
#pragma unroll
        for (int i = 0; i < 6; i++) acc[i] = (f32x4){0, 0, 0, 0};
#pragma unroll
        for (int i = 0; i < 6; i++) {
            acc[i] = MFMA(vf0, wB8[(44 + i * 3 + 0) * 64 + lane], acc[i]);
            acc[i] = MFMA(vf1, wB8[(44 + i * 3 + 1) * 64 + lane], acc[i]);
            acc[i] = MFMA(vf2, wB8[(44 + i * 3 + 2) * 64 + lane], acc[i]);
        }
#pragma unroll
        for (int i = 0; i < 6; i++) {
            int n = i * 16 + ln;
#pragma unroll
            for (int r = 0; r < 4; r++)
                sB[(rC + r) * 104 + n] = f2bf(acc[i][r]);
        }
        // lane -> row lane>>2, 16B chunks (lane&3)+{0,4,8}
        const int rloc = lane >> 2, c0 = lane & 3;
        const int gm = row0 + rloc;
        if (gm < E) {
#pragma unroll
            for (int j = 0; j < 3; j++) {
                short8 v = *(const short8*)&sB[rloc * 104 + (c0 + 4 * j) * 8];
                *(short8*)&value[(size_t)gm * D + (c0 + 4 * j) * 8] = v;
            }
        }
    }
}

// ---------------------------------------------------------------------------
// Fused segment softmax + weighted aggregation: ONE WAVE PER NODE.
// Phase 1: lanes = (8 edges x 8 heads), coalesced 256B logits reads,
//          shfl_xor(8/16/32) reductions -> every lane holds m,z of h=lane&7.
// Phase 2: lanes 0..47 each own a 2-column pair (one uint of bf16 value),
//          stream value rows exactly once (192B/row, coalesced), recompute
//          alpha = exp(logit - m) on the fly, normalize by 1/z at the end.
// ---------------------------------------------------------------------------
__global__ __launch_bounds__(256) void node_kernel(
    const float* __restrict__ logits, const ushort* __restrict__ value,
    const int* __restrict__ rp, ushort* __restrict__ attnB, int N)
{
    const int wid  = (blockIdx.x * 256 + threadIdx.x) >> 6;  // node id
    const int lane = threadIdx.x & 63;
    if (wid >= N) return;
    const int s  = rp[wid];
    const int e1 = rp[wid + 1];

    const int h = lane & 7, eo = lane >> 3;
    float m = -INFINITY;
    for (int e = s + eo; e < e1; e += 8)
        m = fmaxf(m, logits[(size_t)e * H + h]);
    m = fmaxf(m, __shfl_xor(m, 8));
    m = fmaxf(m, __shfl_xor(m, 16));
    m = fmaxf(m, __shfl_xor(m, 32));
    float z = 0.0f;
    for (int e = s + eo; e < e1; e += 8)
        z += __expf(logits[(size_t)e * H + h] - m);
    z += __shfl_xor(z, 8);
    z += __shfl_xor(z, 16);
    z += __shfl_xor(z, 32);
    // every lane now holds m,z for head (lane&7)

    if (lane < 48) {
        const int   hc  = lane / 6;           // head of this column pair
        const float mh  = __shfl(m, hc);      // lane hc holds head hc
        const float zv  = __shfl(z, hc);
        const float zih = (zv > 0.0f) ? (1.0f / zv) : 0.0f;
        const int c = 2 * lane;
        float a0 = 0.0f, a1 = 0.0f;
        for (int e = s; e < e1; e++) {
            float a = __expf(logits[(size_t)e * H + hc] - mh);
            unsigned v = *(const unsigned*)&value[(size_t)e * D + c];
            a0 += __uint_as_float(v << 16) * a;
            a1 += __uint_as_float(v & 0xffff0000u) * a;
        }
        unsigned lo = (unsigned)(ushort)f2bf(a0 * zih);
        unsigned hi = (unsigned)(ushort)f2bf(a1 * zih);
        *(unsigned*)&attnB[(size_t)wid * D + c] = lo | (hi << 16);
    }
}

// ---------------------------------------------------------------------------
// proj: out = attn(bf16) @ W_proj via MFMA. W_proj frags 62..79 in wB.
// ---------------------------------------------------------------------------
__global__ __launch_bounds__(256) void proj_kernel(
    const ushort* __restrict__ attnB, const short* __restrict__ wB,
    float* __restrict__ out, int rows)
{
    const short8* wB8 = (const short8*)wB;
    const int t    = threadIdx.x;
    const int lane = t & 63;
    const int w    = t >> 6;
    const int q    = lane >> 4;
    const int ln   = lane & 15;
    const int row0 = blockIdx.x * 64;
    const int mA   = w * 16 + ln;
    const int gA   = row0 + mA;
    const int mC   = w * 16 + q * 4;

    short8 mf0 = {0, 0, 0, 0, 0, 0, 0, 0}, mf1 = mf0, mf2 = mf0;
    if (gA < rows) {
        mf0 = *(const short8*)&attnB[(size_t)gA * D + 0  + q * 8];
        mf1 = *(const short8*)&attnB[(size_t)gA * D + 32 + q * 8];
        mf2 = *(const short8*)&attnB[(size_t)gA * D + 64 + q * 8];
    }
    f32x4 acc[6];
#pragma unroll
    for (int i = 0; i < 6; i++) acc[i] = (f32x4){0, 0, 0, 0};
#pragma unroll
    for (int i = 0; i < 6; i++) {
        acc[i] = MFMA(mf0, wB8[(62 + i * 3 + 0) * 64 + lane], acc[i]);
        acc[i] = MFMA(mf1, wB8[(62 + i * 3 + 1) * 64 + lane], acc[i]);
        acc[i] = MFMA(mf2, wB8[(62 + i * 3 + 2) * 64 + lane], acc[i]);
    }
#pragma unroll
    for (int i = 0; i < 6; i++) {
        int nn = i * 16 + ln;
#pragma unroll
        for (int r = 0; r < 4; r++) {
            int gm = row0 + mC + r;
            if (gm < rows) out[(size_t)gm * D + nn] = acc[i][r];
        }
    }
}

// ---------------------------------------------------------------------------
extern "C" void kernel_launch(void* const* d_in, const int* in_sizes, int n_in,
                              void* d_out, int out_size, void* d_ws, size_t ws_size,
                              hipStream_t stream)
{
    const float* message      = (const float*)d_in[0];
    const float* edge_attr    = (const float*)d_in[1];
    const float* edge_scalars = (const float*)d_in[2];
    const float* W_rad1       = (const float*)d_in[3];
    const float* b_rad1       = (const float*)d_in[4];
    const float* W_rad2       = (const float*)d_in[5];
    const float* b_rad2       = (const float*)d_in[6];
    const float* W_alpha      = (const float*)d_in[7];
    const float* W_lin        = (const float*)d_in[8];
    const float* w_dtp2       = (const float*)d_in[9];
    const float* W_lin2       = (const float*)d_in[10];
    const float* alpha_dot    = (const float*)d_in[11];
    const float* W_proj       = (const float*)d_in[12];
    const int*   edge_dst     = (const int*)d_in[13];
    float* out = (float*)d_out;

    const int E = in_sizes[0] / D;
    const int N = out_size / D;

    char* p = (char*)d_ws;
    ushort* value  = (ushort*)p;  p += (size_t)E * D * 2;
    float*  logits = (float*)p;   p += (size_t)E * H * 4;
    ushort* attnB  = (ushort*)p;  p += ((size_t)N * D * 2 + 15) & ~(size_t)15;
    int*    rp     = (int*)p;     p += ((size_t)(N + 1) * 4 + 15) & ~(size_t)15;
    short*  wBuf   = (short*)p;   // 83*512 bf16

    pack_weights_kernel<<<(83 * 512 + 255) / 256, 256, 0, stream>>>(
        W_rad1, W_rad2, W_alpha, W_lin, W_lin2, W_proj, alpha_dot, wBuf);
    rowptr_kernel<<<(E + 255) / 256, 256, 0, stream>>>(edge_dst, rp, E, N);
    fused_edge_kernel<<<(E + 63) / 64, 256, 0, stream>>>(
        message, edge_attr, edge_scalars, b_rad1, b_rad2, w_dtp2,
        wBuf, value, logits, E);
    node_kernel<<<(N + 3) / 4, 256, 0, stream>>>(logits, value, rp, attnB, N);
    proj_kernel<<<(N + 63) / 64, 256, 0, stream>>>(attnB, wBuf, out, N);
}